// Round 1
// baseline (1356.273 us; speedup 1.0000x reference)
//
#include <hip/hip_runtime.h>
#include <cstdint>
#include <cstddef>
#include <cmath>

// ---------------- problem constants ----------------
static constexpr int N1v = 123904;   // layer0 targets
static constexpr int N2v = 11264;    // layer1 targets
static constexpr int N3v = 1024;     // layer2 targets

// ============================================================
// CSR build: count -> exclusive scan (3 pass) -> fill
// ============================================================
__global__ void count_tgt(const int* __restrict__ ei, int E, int* __restrict__ cnt) {
    int e = blockIdx.x * 256 + threadIdx.x;
    if (e < E) atomicAdd(&cnt[ei[E + e]], 1);
}

// block handles 1024 elements (256 thr x 4). writes per-block exclusive scan + block sum.
__global__ void scan_pass1(const int* __restrict__ in, int* __restrict__ out,
                           int* __restrict__ bsums, int n) {
    __shared__ int sh[256];
    int tid = threadIdx.x;
    int base = blockIdx.x * 1024 + tid * 4;
    int v0 = (base + 0 < n) ? in[base + 0] : 0;
    int v1 = (base + 1 < n) ? in[base + 1] : 0;
    int v2 = (base + 2 < n) ? in[base + 2] : 0;
    int v3 = (base + 3 < n) ? in[base + 3] : 0;
    int tsum = v0 + v1 + v2 + v3;
    int val = tsum;
    sh[tid] = val;
    __syncthreads();
    for (int off = 1; off < 256; off <<= 1) {
        int other = (tid >= off) ? sh[tid - off] : 0;
        __syncthreads();
        val += other;
        sh[tid] = val;
        __syncthreads();
    }
    int excl = val - tsum;
    if (base + 0 < n) out[base + 0] = excl;
    if (base + 1 < n) out[base + 1] = excl + v0;
    if (base + 2 < n) out[base + 2] = excl + v0 + v1;
    if (base + 3 < n) out[base + 3] = excl + v0 + v1 + v2;
    if (tid == 255) bsums[blockIdx.x] = val;  // inclusive total of this block
}

__global__ void scan_pass2(int* bsums, int nb) {
    __shared__ int sh[256];
    int tid = threadIdx.x;
    int v = (tid < nb) ? bsums[tid] : 0;
    int val = v;
    sh[tid] = val;
    __syncthreads();
    for (int off = 1; off < 256; off <<= 1) {
        int other = (tid >= off) ? sh[tid - off] : 0;
        __syncthreads();
        val += other;
        sh[tid] = val;
        __syncthreads();
    }
    if (tid < nb) bsums[tid] = val - v;  // exclusive
}

__global__ void scan_pass3(int* __restrict__ out, const int* __restrict__ bsums,
                           int n, int total) {
    int i = blockIdx.x * 256 + threadIdx.x;
    if (i < n) out[i] += bsums[i >> 10];
    if (i == 0) out[n] = total;
}

__global__ void fill_csr(const int* __restrict__ ei, int E, const int* __restrict__ off,
                         int* __restrict__ cur, int* __restrict__ srcs) {
    int e = blockIdx.x * 256 + threadIdx.x;
    if (e >= E) return;
    int t = ei[E + e];
    int pos = off[t] + atomicAdd(&cur[t], 1);
    srcs[pos] = ei[e];
}

// ============================================================
// Mean aggregation: one wave (64 lanes) per target node.
// C floats per row; lane holds C/64 consecutive floats in registers.
// ============================================================
template <int C>
__global__ void aggregate_mean(const float* __restrict__ x, const int* __restrict__ off,
                               const int* __restrict__ srcs, float* __restrict__ agg,
                               int n_tgt) {
    constexpr int VPT = C / 64;
    int gwave = (blockIdx.x * blockDim.x + threadIdx.x) >> 6;
    int lane = threadIdx.x & 63;
    if (gwave >= n_tgt) return;
    int beg = off[gwave], end = off[gwave + 1];
    float acc[VPT];
#pragma unroll
    for (int j = 0; j < VPT; ++j) acc[j] = 0.f;
#pragma unroll 4
    for (int e = beg; e < end; ++e) {
        int s = srcs[e];
        const float* row = x + (size_t)s * C + lane * VPT;
        if (VPT == 2) {
            float2 v = *(const float2*)row;
            acc[0] += v.x; acc[1] += v.y;
        } else {
            float4 v = *(const float4*)row;
            acc[0] += v.x; acc[1] += v.y; acc[2] += v.z; acc[3] += v.w;
        }
    }
    int deg = end - beg;
    float inv = 1.0f / (float)(deg > 0 ? deg : 1);
    float* o = agg + (size_t)gwave * C + lane * VPT;
    if (VPT == 2) {
        float2 r; r.x = acc[0] * inv; r.y = acc[1] * inv;
        *(float2*)o = r;
    } else {
        float4 r; r.x = acc[0] * inv; r.y = acc[1] * inv; r.z = acc[2] * inv; r.w = acc[3] * inv;
        *(float4*)o = r;
    }
}

// ============================================================
// Fused GEMM: out[M x 256] = A1 @ B1 + A2 @ B2 + bias, optional relu.
// A1,A2: M x KHALF row-major. B1,B2: KHALF x 256 row-major.
// Block: 256 thr, tile BM=64 x BN=256, k-step 32.
// Thread micro-tile: 16 rows x 4 cols (float4 acc).
// ============================================================
template <int KHALF>
__global__ __launch_bounds__(256) void gemm_fused(
    const float* __restrict__ A1, const float* __restrict__ A2,
    const float* __restrict__ B1, const float* __restrict__ B2,
    const float* __restrict__ bias, float* __restrict__ out, bool relu) {
    constexpr int KTOT = 2 * KHALF;
    constexpr int BN = 256, KS = 32;
    __shared__ float As[KS][68];   // [k][row], padded to spread staging-write banks
    __shared__ float Bs[KS][BN];   // [k][col]

    int tid = threadIdx.x;
    int r0 = blockIdx.x * 64;
    int w = tid >> 6;        // wave 0..3 -> 64-col slice
    int l = tid & 63;
    int cg = l & 15;         // col group within wave
    int rg = l >> 4;         // row group: rows rg*16 .. rg*16+15
    int col = w * 64 + cg * 4;
    int rg16 = rg * 16;

    float4 acc[16];
#pragma unroll
    for (int i = 0; i < 16; ++i) acc[i] = make_float4(0.f, 0.f, 0.f, 0.f);

    for (int kt = 0; kt < KTOT; kt += KS) {
        const float* Asrc = (kt < KHALF) ? A1 : A2;
        const float* Bsrc = (kt < KHALF) ? B1 : B2;
        int kk0 = (kt < KHALF) ? kt : kt - KHALF;
        // stage A tile (64 rows x 32 k), transposed into As[k][row]
#pragma unroll
        for (int it = 0; it < 2; ++it) {
            int idx = it * 256 + tid;      // 0..511
            int row = idx >> 3;            // 0..63
            int kq = (idx & 7) * 4;        // 0..28
            float4 v = *(const float4*)(Asrc + (size_t)(r0 + row) * KHALF + kk0 + kq);
            As[kq + 0][row] = v.x;
            As[kq + 1][row] = v.y;
            As[kq + 2][row] = v.z;
            As[kq + 3][row] = v.w;
        }
        // stage B tile (32 k x 256 cols)
#pragma unroll
        for (int it = 0; it < 8; ++it) {
            int idx = it * 256 + tid;      // 0..2047
            int kk = idx >> 6;             // 0..31
            int n4 = (idx & 63) * 4;       // 0..252
            *(float4*)&Bs[kk][n4] = *(const float4*)(Bsrc + (size_t)(kk0 + kk) * BN + n4);
        }
        __syncthreads();
#pragma unroll 8
        for (int kk = 0; kk < KS; ++kk) {
            const float4 b = *(const float4*)&Bs[kk][col];
            const float4 a0 = *(const float4*)&As[kk][rg16 + 0];
            const float4 a1 = *(const float4*)&As[kk][rg16 + 4];
            const float4 a2 = *(const float4*)&As[kk][rg16 + 8];
            const float4 a3 = *(const float4*)&As[kk][rg16 + 12];
#define FMA_ROW(I, S) \
            acc[I].x += (S) * b.x; acc[I].y += (S) * b.y; \
            acc[I].z += (S) * b.z; acc[I].w += (S) * b.w;
            FMA_ROW(0, a0.x) FMA_ROW(1, a0.y) FMA_ROW(2, a0.z) FMA_ROW(3, a0.w)
            FMA_ROW(4, a1.x) FMA_ROW(5, a1.y) FMA_ROW(6, a1.z) FMA_ROW(7, a1.w)
            FMA_ROW(8, a2.x) FMA_ROW(9, a2.y) FMA_ROW(10, a2.z) FMA_ROW(11, a2.w)
            FMA_ROW(12, a3.x) FMA_ROW(13, a3.y) FMA_ROW(14, a3.z) FMA_ROW(15, a3.w)
#undef FMA_ROW
        }
        __syncthreads();
    }
    float4 bv = *(const float4*)(bias + col);
#pragma unroll
    for (int i = 0; i < 16; ++i) {
        float4 r;
        r.x = acc[i].x + bv.x;
        r.y = acc[i].y + bv.y;
        r.z = acc[i].z + bv.z;
        r.w = acc[i].w + bv.w;
        if (relu) {
            r.x = fmaxf(r.x, 0.f); r.y = fmaxf(r.y, 0.f);
            r.z = fmaxf(r.z, 0.f); r.w = fmaxf(r.w, 0.f);
        }
        *(float4*)(out + (size_t)(r0 + rg16 + i) * BN + col) = r;
    }
}

// ============================================================
// Layer 2 (N=47) + log_softmax, one wave per output row.
// logits[n] = sum_k agg[k]*Wl2[k][n] + sum_k xt[k]*Wr2[k][n] + b[n]
// ============================================================
__global__ void layer2_logsoftmax(const float* __restrict__ agg, const float* __restrict__ xt,
                                  const float* __restrict__ Wl, const float* __restrict__ Wr,
                                  const float* __restrict__ b, float* __restrict__ out) {
    __shared__ float a[512];
    int row = blockIdx.x;
    int tid = threadIdx.x;  // 64 threads
#pragma unroll
    for (int i = 0; i < 4; ++i) {
        a[tid + i * 64] = agg[(size_t)row * 256 + tid + i * 64];
        a[256 + tid + i * 64] = xt[(size_t)row * 256 + tid + i * 64];
    }
    __syncthreads();
    float v = -INFINITY;
    if (tid < 47) {
        float s0 = b[tid], s1 = 0.f, s2 = 0.f, s3 = 0.f;
#pragma unroll 4
        for (int k = 0; k < 256; k += 4) {
            s0 += a[k + 0] * Wl[(k + 0) * 47 + tid];
            s1 += a[k + 1] * Wl[(k + 1) * 47 + tid];
            s2 += a[k + 2] * Wl[(k + 2) * 47 + tid];
            s3 += a[k + 3] * Wl[(k + 3) * 47 + tid];
        }
#pragma unroll 4
        for (int k = 0; k < 256; k += 4) {
            s0 += a[256 + k + 0] * Wr[(k + 0) * 47 + tid];
            s1 += a[256 + k + 1] * Wr[(k + 1) * 47 + tid];
            s2 += a[256 + k + 2] * Wr[(k + 2) * 47 + tid];
            s3 += a[256 + k + 3] * Wr[(k + 3) * 47 + tid];
        }
        v = (s0 + s1) + (s2 + s3);
    }
    // wave-wide max / sum-exp (lanes >= 47 contribute -inf / 0)
    float m = v;
#pragma unroll
    for (int off = 32; off > 0; off >>= 1) m = fmaxf(m, __shfl_xor(m, off));
    float ex = (tid < 47) ? expf(v - m) : 0.f;
    float sum = ex;
#pragma unroll
    for (int off = 32; off > 0; off >>= 1) sum += __shfl_xor(sum, off);
    if (tid < 47) out[(size_t)row * 47 + tid] = (v - m) - logf(sum);
}

// ============================================================
extern "C" void kernel_launch(void* const* d_in, const int* in_sizes, int n_in,
                              void* d_out, int out_size, void* d_ws, size_t ws_size,
                              hipStream_t stream) {
    const float* x   = (const float*)d_in[0];
    const int*  ei0  = (const int*)d_in[1];
    const int*  ei1  = (const int*)d_in[2];
    const int*  ei2  = (const int*)d_in[3];
    const float* Wl0 = (const float*)d_in[4];
    const float* Wr0 = (const float*)d_in[5];
    const float* b0  = (const float*)d_in[6];
    const float* Wl1 = (const float*)d_in[7];
    const float* Wr1 = (const float*)d_in[8];
    const float* b1  = (const float*)d_in[9];
    const float* Wl2 = (const float*)d_in[10];
    const float* Wr2 = (const float*)d_in[11];
    const float* b2  = (const float*)d_in[12];
    float* out = (float*)d_out;

    const int E0 = in_sizes[1] / 2;   // 1239040
    const int E1 = in_sizes[2] / 2;   // 112640
    const int E2 = in_sizes[3] / 2;   // 10240

    // ---- workspace carve-up (~222 MB) ----
    char* w = (char*)d_ws;
    auto take = [&](size_t bytes) -> char* {
        char* p = w;
        w += (bytes + 255) & ~(size_t)255;
        return p;
    };
    float* h0   = (float*)take((size_t)N1v * 256 * 4);   // 126.9 MB
    float* agg0 = (float*)take((size_t)N1v * 128 * 4);   // 63.4 MB
    float* h1   = (float*)take((size_t)N2v * 256 * 4);   // 11.5 MB
    float* agg1 = (float*)take((size_t)N2v * 256 * 4);   // 11.5 MB
    float* agg2 = (float*)take((size_t)N3v * 256 * 4);   // 1.0 MB
    int* off0  = (int*)take((size_t)(N1v + 1) * 4);
    int* srcs0 = (int*)take((size_t)E0 * 4);
    int* off1  = (int*)take((size_t)(N2v + 1) * 4);
    int* srcs1 = (int*)take((size_t)E1 * 4);
    int* off2  = (int*)take((size_t)(N3v + 1) * 4);
    int* srcs2 = (int*)take((size_t)E2 * 4);
    int* tmp0  = (int*)take((size_t)(N1v + N2v + N3v) * 4);  // contiguous counters
    int* tmp1  = tmp0 + N1v;
    int* tmp2  = tmp1 + N2v;
    int* bsums = (int*)take(1024);

    const size_t tmpBytes = (size_t)(N1v + N2v + N3v) * 4;

    // ---- CSR build (all 3 layers) ----
    hipMemsetAsync(tmp0, 0, tmpBytes, stream);
    count_tgt<<<(E0 + 255) / 256, 256, 0, stream>>>(ei0, E0, tmp0);
    count_tgt<<<(E1 + 255) / 256, 256, 0, stream>>>(ei1, E1, tmp1);
    count_tgt<<<(E2 + 255) / 256, 256, 0, stream>>>(ei2, E2, tmp2);

    scan_pass1<<<(N1v + 1023) / 1024, 256, 0, stream>>>(tmp0, off0, bsums, N1v);
    scan_pass2<<<1, 256, 0, stream>>>(bsums, (N1v + 1023) / 1024);
    scan_pass3<<<(N1v + 255) / 256, 256, 0, stream>>>(off0, bsums, N1v, E0);

    scan_pass1<<<(N2v + 1023) / 1024, 256, 0, stream>>>(tmp1, off1, bsums, N2v);
    scan_pass2<<<1, 256, 0, stream>>>(bsums, (N2v + 1023) / 1024);
    scan_pass3<<<(N2v + 255) / 256, 256, 0, stream>>>(off1, bsums, N2v, E1);

    scan_pass1<<<(N3v + 1023) / 1024, 256, 0, stream>>>(tmp2, off2, bsums, N3v);
    scan_pass2<<<1, 256, 0, stream>>>(bsums, (N3v + 1023) / 1024);
    scan_pass3<<<(N3v + 255) / 256, 256, 0, stream>>>(off2, bsums, N3v, E2);

    hipMemsetAsync(tmp0, 0, tmpBytes, stream);
    fill_csr<<<(E0 + 255) / 256, 256, 0, stream>>>(ei0, E0, off0, tmp0, srcs0);
    fill_csr<<<(E1 + 255) / 256, 256, 0, stream>>>(ei1, E1, off1, tmp1, srcs1);
    fill_csr<<<(E2 + 255) / 256, 256, 0, stream>>>(ei2, E2, off2, tmp2, srcs2);

    // ---- layer 0 ----
    aggregate_mean<128><<<(N1v + 3) / 4, 256, 0, stream>>>(x, off0, srcs0, agg0, N1v);
    gemm_fused<128><<<N1v / 64, 256, 0, stream>>>(agg0, x, Wl0, Wr0, b0, h0, true);

    // ---- layer 1 ----
    aggregate_mean<256><<<(N2v + 3) / 4, 256, 0, stream>>>(h0, off1, srcs1, agg1, N2v);
    gemm_fused<256><<<N2v / 64, 256, 0, stream>>>(agg1, h0, Wl1, Wr1, b1, h1, true);

    // ---- layer 2 + log_softmax ----
    aggregate_mean<256><<<(N3v + 3) / 4, 256, 0, stream>>>(h1, off2, srcs2, agg2, N3v);
    layer2_logsoftmax<<<N3v, 64, 0, stream>>>(agg2, h1, Wl2, Wr2, b2, out);
}

// Round 3
// 1219.410 us; speedup vs baseline: 1.1122x; 1.1122x over previous
//
#include <hip/hip_runtime.h>
#include <cstdint>
#include <cstddef>
#include <cmath>

// ---------------- problem constants ----------------
static constexpr int N1v = 123904;   // layer0 targets
static constexpr int N2v = 11264;    // layer1 targets
static constexpr int N3v = 1024;     // layer2 targets

typedef __bf16 bf16x8 __attribute__((ext_vector_type(8)));
typedef unsigned short u16x8 __attribute__((ext_vector_type(8)));
typedef float f32x4 __attribute__((ext_vector_type(4)));

__device__ __forceinline__ unsigned short f2bf(float f) {
    uint32_t u = __float_as_uint(f);
    uint32_t r = (u + 0x7FFFu + ((u >> 16) & 1u)) >> 16;   // RTNE
    return (unsigned short)r;
}
__device__ __forceinline__ float bf2f(unsigned short h) {
    return __uint_as_float(((uint32_t)h) << 16);
}

// ============================================================
// CSR build: count -> exclusive scan (3 pass) -> fill
// ============================================================
__global__ void count_tgt(const int* __restrict__ ei, int E, int* __restrict__ cnt) {
    int e = blockIdx.x * 256 + threadIdx.x;
    if (e < E) atomicAdd(&cnt[ei[E + e]], 1);
}

__global__ void scan_pass1(const int* __restrict__ in, int* __restrict__ out,
                           int* __restrict__ bsums, int n) {
    __shared__ int sh[256];
    int tid = threadIdx.x;
    int base = blockIdx.x * 1024 + tid * 4;
    int v0 = (base + 0 < n) ? in[base + 0] : 0;
    int v1 = (base + 1 < n) ? in[base + 1] : 0;
    int v2 = (base + 2 < n) ? in[base + 2] : 0;
    int v3 = (base + 3 < n) ? in[base + 3] : 0;
    int tsum = v0 + v1 + v2 + v3;
    int val = tsum;
    sh[tid] = val;
    __syncthreads();
    for (int off = 1; off < 256; off <<= 1) {
        int other = (tid >= off) ? sh[tid - off] : 0;
        __syncthreads();
        val += other;
        sh[tid] = val;
        __syncthreads();
    }
    int excl = val - tsum;
    if (base + 0 < n) out[base + 0] = excl;
    if (base + 1 < n) out[base + 1] = excl + v0;
    if (base + 2 < n) out[base + 2] = excl + v0 + v1;
    if (base + 3 < n) out[base + 3] = excl + v0 + v1 + v2;
    if (tid == 255) bsums[blockIdx.x] = val;
}

__global__ void scan_pass2(int* bsums, int nb) {
    __shared__ int sh[256];
    int tid = threadIdx.x;
    int v = (tid < nb) ? bsums[tid] : 0;
    int val = v;
    sh[tid] = val;
    __syncthreads();
    for (int off = 1; off < 256; off <<= 1) {
        int other = (tid >= off) ? sh[tid - off] : 0;
        __syncthreads();
        val += other;
        sh[tid] = val;
        __syncthreads();
    }
    if (tid < nb) bsums[tid] = val - v;
}

__global__ void scan_pass3(int* __restrict__ out, const int* __restrict__ bsums,
                           int n, int total) {
    int i = blockIdx.x * 256 + threadIdx.x;
    if (i < n) out[i] += bsums[i >> 10];
    if (i == 0) out[n] = total;
}

__global__ void fill_csr(const int* __restrict__ ei, int E, const int* __restrict__ off,
                         int* __restrict__ cur, int* __restrict__ srcs) {
    int e = blockIdx.x * 256 + threadIdx.x;
    if (e >= E) return;
    int t = ei[E + e];
    int pos = off[t] + atomicAdd(&cur[t], 1);
    srcs[pos] = ei[e];
}

// ============================================================
// Mean aggregation: one wave per target node (unchanged this round).
// ============================================================
template <int C>
__global__ void aggregate_mean(const float* __restrict__ x, const int* __restrict__ off,
                               const int* __restrict__ srcs, float* __restrict__ agg,
                               int n_tgt) {
    constexpr int VPT = C / 64;
    int gwave = (blockIdx.x * blockDim.x + threadIdx.x) >> 6;
    int lane = threadIdx.x & 63;
    if (gwave >= n_tgt) return;
    int beg = off[gwave], end = off[gwave + 1];
    float acc[VPT];
#pragma unroll
    for (int j = 0; j < VPT; ++j) acc[j] = 0.f;
#pragma unroll 4
    for (int e = beg; e < end; ++e) {
        int s = srcs[e];
        const float* row = x + (size_t)s * C + lane * VPT;
        if (VPT == 2) {
            float2 v = *(const float2*)row;
            acc[0] += v.x; acc[1] += v.y;
        } else {
            float4 v = *(const float4*)row;
            acc[0] += v.x; acc[1] += v.y; acc[2] += v.z; acc[3] += v.w;
        }
    }
    int deg = end - beg;
    float inv = 1.0f / (float)(deg > 0 ? deg : 1);
    float* o = agg + (size_t)gwave * C + lane * VPT;
    if (VPT == 2) {
        float2 r; r.x = acc[0] * inv; r.y = acc[1] * inv;
        *(float2*)o = r;
    } else {
        float4 r; r.x = acc[0] * inv; r.y = acc[1] * inv; r.z = acc[2] * inv; r.w = acc[3] * inv;
        *(float4*)o = r;
    }
}

// ============================================================
// One-time weight prep: W combined [2*KH x 256] fp32 ->
// transposed K-major bf16 hi/lo: Bt[n][k], n=0..255, k=0..2*KH-1.
// ============================================================
template <int KH>
__global__ void split_transpose_B(const float* __restrict__ Wl, const float* __restrict__ Wr,
                                  unsigned short* __restrict__ Bth,
                                  unsigned short* __restrict__ Btl) {
    constexpr int KTOT = 2 * KH;
    int idx = blockIdx.x * 256 + threadIdx.x;
    if (idx >= KTOT * 256) return;
    int k = idx >> 8;
    int n = idx & 255;
    float v = (k < KH) ? Wl[(size_t)k * 256 + n] : Wr[(size_t)(k - KH) * 256 + n];
    unsigned short h = f2bf(v);
    Bth[(size_t)n * KTOT + k] = h;
    Btl[(size_t)n * KTOT + k] = f2bf(v - bf2f(h));
}

// ============================================================
// Split-bf16 MFMA GEMM:
// out[M x 256] = relu?( A1@B1 + A2@B2 + bias )
// A1,A2: M x KHALF fp32 row-major (converted hi/lo in-kernel).
// B provided pre-transposed/split: Bt[n][k] bf16 hi/lo, k over 2*KHALF.
// 3-term split product: AhBh + AhBl + AlBh (AlBl ~2^-18, dropped).
// Block: 512 thr (8 waves), tile 128 x 256, k-step 32.
// Wave (wr,wc): 64x64 sub-tile = 4x4 fragments of 16x16x32 MFMA.
// ============================================================
template <int KHALF>
__global__ __launch_bounds__(512) void gemm_mfma(
    const float* __restrict__ A1, const float* __restrict__ A2,
    const unsigned short* __restrict__ Bth, const unsigned short* __restrict__ Btl,
    const float* __restrict__ bias, float* __restrict__ out, int relu) {
    constexpr int KTOT = 2 * KHALF;
    constexpr int BM = 128, BN = 256, BK = 32, LDA = 40;  // pad 32->40 bf16 (80B rows)
    __shared__ unsigned short Ah[BM][LDA], Al[BM][LDA];
    __shared__ unsigned short Bh[BN][LDA], Bl[BN][LDA];

    int tid = threadIdx.x;
    int wid = tid >> 6, lane = tid & 63;
    int wr = wid >> 2, wc = wid & 3;       // 2 x 4 wave grid
    int l15 = lane & 15, lk = lane >> 4;   // MFMA fragment coords
    int r0 = blockIdx.x * BM;

    f32x4 acc[4][4] = {};

    for (int kt = 0; kt < KTOT; kt += BK) {
        const float* Asrc = (kt < KHALF) ? A1 : A2;
        int kk0 = (kt < KHALF) ? kt : kt - KHALF;

        // ---- stage A: 128 rows x 32 k, fp32 -> hi/lo bf16 ----
        {
            int row = tid >> 2;            // 0..127
            int k0 = (tid & 3) * 8;        // 0,8,16,24
            const float* src = Asrc + (size_t)(r0 + row) * KHALF + kk0 + k0;
            float4 v0 = *(const float4*)(src);
            float4 v1 = *(const float4*)(src + 4);
            float f[8] = {v0.x, v0.y, v0.z, v0.w, v1.x, v1.y, v1.z, v1.w};
            u16x8 h, lo;
#pragma unroll
            for (int j = 0; j < 8; ++j) {
                unsigned short hh = f2bf(f[j]);
                h[j] = hh;
                lo[j] = f2bf(f[j] - bf2f(hh));
            }
            *(u16x8*)&Ah[row][k0] = h;
            *(u16x8*)&Al[row][k0] = lo;
        }
        // ---- stage B: 256 cols x 32 k from pre-split K-major bf16 ----
        {
            int col = tid >> 1;            // 0..255
            int k0 = (tid & 1) * 16;       // 0,16
            const unsigned short* gh = Bth + (size_t)col * KTOT + kt + k0;
            const unsigned short* gl = Btl + (size_t)col * KTOT + kt + k0;
            *(u16x8*)&Bh[col][k0]     = *(const u16x8*)gh;
            *(u16x8*)&Bh[col][k0 + 8] = *(const u16x8*)(gh + 8);
            *(u16x8*)&Bl[col][k0]     = *(const u16x8*)gl;
            *(u16x8*)&Bl[col][k0 + 8] = *(const u16x8*)(gl + 8);
        }
        __syncthreads();

        // ---- fragments: A row = l15, k = lk*8+j ; B col = l15, k = lk*8+j ----
        bf16x8 ah[4], al[4], bh[4], bl[4];
#pragma unroll
        for (int m = 0; m < 4; ++m) {
            int row = wr * 64 + m * 16 + l15;
            ah[m] = __builtin_bit_cast(bf16x8, *(const u16x8*)&Ah[row][lk * 8]);
            al[m] = __builtin_bit_cast(bf16x8, *(const u16x8*)&Al[row][lk * 8]);
        }
#pragma unroll
        for (int n = 0; n < 4; ++n) {
            int col = wc * 64 + n * 16 + l15;
            bh[n] = __builtin_bit_cast(bf16x8, *(const u16x8*)&Bh[col][lk * 8]);
            bl[n] = __builtin_bit_cast(bf16x8, *(const u16x8*)&Bl[col][lk * 8]);
        }
#pragma unroll
        for (int m = 0; m < 4; ++m)
#pragma unroll
            for (int n = 0; n < 4; ++n) {
                acc[m][n] = __builtin_amdgcn_mfma_f32_16x16x32_bf16(ah[m], bh[n], acc[m][n], 0, 0, 0);
                acc[m][n] = __builtin_amdgcn_mfma_f32_16x16x32_bf16(ah[m], bl[n], acc[m][n], 0, 0, 0);
                acc[m][n] = __builtin_amdgcn_mfma_f32_16x16x32_bf16(al[m], bh[n], acc[m][n], 0, 0, 0);
            }
        __syncthreads();
    }

    // ---- epilogue: C/D layout col=lane&15, row=(lane>>4)*4+reg ----
#pragma unroll
    for (int n = 0; n < 4; ++n) {
        int col = wc * 64 + n * 16 + l15;
        float bv = bias[col];
#pragma unroll
        for (int m = 0; m < 4; ++m) {
            int rbase = r0 + wr * 64 + m * 16 + lk * 4;
#pragma unroll
            for (int i = 0; i < 4; ++i) {
                float v = acc[m][n][i] + bv;
                if (relu) v = fmaxf(v, 0.f);
                out[(size_t)(rbase + i) * BN + col] = v;
            }
        }
    }
}

// ============================================================
// Layer 2 (N=47) + log_softmax, one wave per output row.
// ============================================================
__global__ void layer2_logsoftmax(const float* __restrict__ agg, const float* __restrict__ xt,
                                  const float* __restrict__ Wl, const float* __restrict__ Wr,
                                  const float* __restrict__ b, float* __restrict__ out) {
    __shared__ float a[512];
    int row = blockIdx.x;
    int tid = threadIdx.x;  // 64 threads
#pragma unroll
    for (int i = 0; i < 4; ++i) {
        a[tid + i * 64] = agg[(size_t)row * 256 + tid + i * 64];
        a[256 + tid + i * 64] = xt[(size_t)row * 256 + tid + i * 64];
    }
    __syncthreads();
    float v = -INFINITY;
    if (tid < 47) {
        float s0 = b[tid], s1 = 0.f, s2 = 0.f, s3 = 0.f;
#pragma unroll 4
        for (int k = 0; k < 256; k += 4) {
            s0 += a[k + 0] * Wl[(k + 0) * 47 + tid];
            s1 += a[k + 1] * Wl[(k + 1) * 47 + tid];
            s2 += a[k + 2] * Wl[(k + 2) * 47 + tid];
            s3 += a[k + 3] * Wl[(k + 3) * 47 + tid];
        }
#pragma unroll 4
        for (int k = 0; k < 256; k += 4) {
            s0 += a[256 + k + 0] * Wr[(k + 0) * 47 + tid];
            s1 += a[256 + k + 1] * Wr[(k + 1) * 47 + tid];
            s2 += a[256 + k + 2] * Wr[(k + 2) * 47 + tid];
            s3 += a[256 + k + 3] * Wr[(k + 3) * 47 + tid];
        }
        v = (s0 + s1) + (s2 + s3);
    }
    float m = v;
#pragma unroll
    for (int off = 32; off > 0; off >>= 1) m = fmaxf(m, __shfl_xor(m, off));
    float ex = (tid < 47) ? expf(v - m) : 0.f;
    float sum = ex;
#pragma unroll
    for (int off = 32; off > 0; off >>= 1) sum += __shfl_xor(sum, off);
    if (tid < 47) out[(size_t)row * 47 + tid] = (v - m) - logf(sum);
}

// ============================================================
extern "C" void kernel_launch(void* const* d_in, const int* in_sizes, int n_in,
                              void* d_out, int out_size, void* d_ws, size_t ws_size,
                              hipStream_t stream) {
    const float* x   = (const float*)d_in[0];
    const int*  ei0  = (const int*)d_in[1];
    const int*  ei1  = (const int*)d_in[2];
    const int*  ei2  = (const int*)d_in[3];
    const float* Wl0 = (const float*)d_in[4];
    const float* Wr0 = (const float*)d_in[5];
    const float* b0  = (const float*)d_in[6];
    const float* Wl1 = (const float*)d_in[7];
    const float* Wr1 = (const float*)d_in[8];
    const float* b1  = (const float*)d_in[9];
    const float* Wl2 = (const float*)d_in[10];
    const float* Wr2 = (const float*)d_in[11];
    const float* b2  = (const float*)d_in[12];
    float* out = (float*)d_out;

    const int E0 = in_sizes[1] / 2;   // 1239040
    const int E1 = in_sizes[2] / 2;   // 112640
    const int E2 = in_sizes[3] / 2;   // 10240

    // ---- workspace carve-up ----
    char* w = (char*)d_ws;
    auto take = [&](size_t bytes) -> char* {
        char* p = w;
        w += (bytes + 255) & ~(size_t)255;
        return p;
    };
    float* h0   = (float*)take((size_t)N1v * 256 * 4);
    float* agg0 = (float*)take((size_t)N1v * 128 * 4);
    float* h1   = (float*)take((size_t)N2v * 256 * 4);
    float* agg1 = (float*)take((size_t)N2v * 256 * 4);
    float* agg2 = (float*)take((size_t)N3v * 256 * 4);
    unsigned short* Bt0h = (unsigned short*)take((size_t)256 * 256 * 2);
    unsigned short* Bt0l = (unsigned short*)take((size_t)256 * 256 * 2);
    unsigned short* Bt1h = (unsigned short*)take((size_t)256 * 512 * 2);
    unsigned short* Bt1l = (unsigned short*)take((size_t)256 * 512 * 2);
    int* off0  = (int*)take((size_t)(N1v + 1) * 4);
    int* srcs0 = (int*)take((size_t)E0 * 4);
    int* off1  = (int*)take((size_t)(N2v + 1) * 4);
    int* srcs1 = (int*)take((size_t)E1 * 4);
    int* off2  = (int*)take((size_t)(N3v + 1) * 4);
    int* srcs2 = (int*)take((size_t)E2 * 4);
    int* tmp0  = (int*)take((size_t)(N1v + N2v + N3v) * 4);
    int* tmp1  = tmp0 + N1v;
    int* tmp2  = tmp1 + N2v;
    int* bsums = (int*)take(1024);

    const size_t tmpBytes = (size_t)(N1v + N2v + N3v) * 4;

    // ---- weight prep (independent of CSR) ----
    split_transpose_B<128><<<256, 256, 0, stream>>>(Wl0, Wr0, Bt0h, Bt0l);
    split_transpose_B<256><<<512, 256, 0, stream>>>(Wl1, Wr1, Bt1h, Bt1l);

    // ---- CSR build (all 3 layers) ----
    hipMemsetAsync(tmp0, 0, tmpBytes, stream);
    count_tgt<<<(E0 + 255) / 256, 256, 0, stream>>>(ei0, E0, tmp0);
    count_tgt<<<(E1 + 255) / 256, 256, 0, stream>>>(ei1, E1, tmp1);
    count_tgt<<<(E2 + 255) / 256, 256, 0, stream>>>(ei2, E2, tmp2);

    scan_pass1<<<(N1v + 1023) / 1024, 256, 0, stream>>>(tmp0, off0, bsums, N1v);
    scan_pass2<<<1, 256, 0, stream>>>(bsums, (N1v + 1023) / 1024);
    scan_pass3<<<(N1v + 255) / 256, 256, 0, stream>>>(off0, bsums, N1v, E0);

    scan_pass1<<<(N2v + 1023) / 1024, 256, 0, stream>>>(tmp1, off1, bsums, N2v);
    scan_pass2<<<1, 256, 0, stream>>>(bsums, (N2v + 1023) / 1024);
    scan_pass3<<<(N2v + 255) / 256, 256, 0, stream>>>(off1, bsums, N2v, E1);

    scan_pass1<<<(N3v + 1023) / 1024, 256, 0, stream>>>(tmp2, off2, bsums, N3v);
    scan_pass2<<<1, 256, 0, stream>>>(bsums, (N3v + 1023) / 1024);
    scan_pass3<<<(N3v + 255) / 256, 256, 0, stream>>>(off2, bsums, N3v, E2);

    hipMemsetAsync(tmp0, 0, tmpBytes, stream);
    fill_csr<<<(E0 + 255) / 256, 256, 0, stream>>>(ei0, E0, off0, tmp0, srcs0);
    fill_csr<<<(E1 + 255) / 256, 256, 0, stream>>>(ei1, E1, off1, tmp1, srcs1);
    fill_csr<<<(E2 + 255) / 256, 256, 0, stream>>>(ei2, E2, off2, tmp2, srcs2);

    // ---- layer 0 ----
    aggregate_mean<128><<<(N1v + 3) / 4, 256, 0, stream>>>(x, off0, srcs0, agg0, N1v);
    gemm_mfma<128><<<N1v / 128, 512, 0, stream>>>(agg0, x, Bt0h, Bt0l, b0, h0, 1);

    // ---- layer 1 ----
    aggregate_mean<256><<<(N2v + 3) / 4, 256, 0, stream>>>(h0, off1, srcs1, agg1, N2v);
    gemm_mfma<256><<<N2v / 128, 512, 0, stream>>>(agg1, h0, Bt1h, Bt1l, b1, h1, 1);

    // ---- layer 2 + log_softmax ----
    aggregate_mean<256><<<(N3v + 3) / 4, 256, 0, stream>>>(h1, off2, srcs2, agg2, N3v);
    layer2_logsoftmax<<<N3v, 64, 0, stream>>>(agg2, h1, Wl2, Wr2, b2, out);
}